// Round 9
// baseline (133.203 us; speedup 1.0000x reference)
//
#include <hip/hip_runtime.h>
#include <hip/hip_bf16.h>

typedef __attribute__((ext_vector_type(8))) short short8;
typedef __attribute__((ext_vector_type(4))) float f32x4;
typedef __attribute__((ext_vector_type(16))) float f32x16;
typedef unsigned short us;

#define B_ 2
#define S_ 2048
#define D_ 1024
#define H_ 16
#define DK_ 64
#define QSCALE 0.1803368867f  // log2(e) / 8

__device__ __forceinline__ us f2bf(float f) {
  union { float f; unsigned u; } x; x.f = f;
  unsigned r = x.u + 0x7FFFu + ((x.u >> 16) & 1u);
  return (us)(r >> 16);
}
__device__ __forceinline__ float bf2f(us h) {
  union { unsigned u; float f; } x; x.u = ((unsigned)h) << 16;
  return x.f;
}
__device__ __forceinline__ us f2bf_hw(float f) {
  __hip_bfloat16 h = __float2bfloat16(f);
  return *reinterpret_cast<us*>(&h);
}
__device__ __forceinline__ unsigned cvtpk(float lo, float hi) {
  unsigned r;
  asm("v_cvt_pk_bf16_f32 %0, %1, %2" : "=v"(r) : "v"(lo), "v"(hi));
  return r;
}

__device__ __forceinline__ void gload16(const void* g, void* l) {
  __builtin_amdgcn_global_load_lds((const __attribute__((address_space(1))) void*)g,
                                   (__attribute__((address_space(3))) void*)l, 16, 0, 0);
}

// One kernel for all 7 fp32->bf16 conversions.
__global__ __launch_bounds__(256) void cvt_all(const float* __restrict__ q,
                                               const float* __restrict__ k,
                                               const float* __restrict__ v,
                                               const float* __restrict__ Wq,
                                               const float* __restrict__ Wk,
                                               const float* __restrict__ Wv,
                                               const float* __restrict__ Wo,
                                               us* __restrict__ oq, us* __restrict__ ok,
                                               us* __restrict__ ov, us* __restrict__ oWq,
                                               us* __restrict__ oWk, us* __restrict__ oWv,
                                               us* __restrict__ oWo) {
  int bid = blockIdx.x;
  const float* in; us* out; int off;
  if (bid < 12288) {
    int t = bid >> 12;
    in = (t == 0) ? q : (t == 1) ? k : v;
    out = (t == 0) ? oq : (t == 1) ? ok : ov;
    off = (bid & 4095) * 1024;
  } else {
    int t = (bid - 12288) >> 10;
    in = (t == 0) ? Wq : (t == 1) ? Wk : (t == 2) ? Wv : Wo;
    out = (t == 0) ? oWq : (t == 1) ? oWk : (t == 2) ? oWv : oWo;
    off = ((bid - 12288) & 1023) * 1024;
  }
  int i = off + threadIdx.x * 4;
  float4 val = *reinterpret_cast<const float4*>(in + i);
  ushort4 o;
  o.x = f2bf(val.x); o.y = f2bf(val.y); o.z = f2bf(val.z); o.w = f2bf(val.w);
  *reinterpret_cast<ushort4*>(out + i) = o;
}

__global__ __launch_bounds__(256) void rs_kernel(const float* __restrict__ reaches,
                                                 float* __restrict__ rs) {
  int b = blockIdx.x, t = threadIdx.x;
  float s = 0.f;
  for (int i = t; i < S_; i += 256) s += reaches[b * S_ + i];
  for (int o = 32; o > 0; o >>= 1) s += __shfl_down(s, o, 64);
  __shared__ float tmp[4];
  if ((t & 63) == 0) tmp[t >> 6] = s;
  __syncthreads();
  if (t == 0) rs[b] = tmp[0] + tmp[1] + tmp[2] + tmp[3];
}

// GEMM 128x128 tile, BK=32, triple-buffered LDS + counted vmcnt (T3/T4).
// M=4096, N=1024, K=1024, A row-major, Bt row-major (B^T). bf16 head-split out.
__device__ __forceinline__ void gemm_core_hs(const us* __restrict__ A, const us* __restrict__ Bt,
                                             us* __restrict__ outH, float oscale) {
  __shared__ __align__(16) us lA[3][128 * 32];
  __shared__ __align__(16) us lB[3][128 * 32];
  const int tid = threadIdx.x;
  const int bm = blockIdx.x >> 3, bn = blockIdx.x & 7;
  const int w = tid >> 6, lane = tid & 63;
  const int wr = (w >> 1) * 64, wc = (w & 1) * 64;
  const int lr = lane & 15, lg = lane >> 4;

  f32x4 acc[4][4];
#pragma unroll
  for (int i = 0; i < 4; ++i)
#pragma unroll
    for (int j = 0; j < 4; ++j) acc[i][j] = (f32x4){0.f, 0.f, 0.f, 0.f};

  const int crow = lane >> 2, ce8 = (lane & 3) * 8;
  const us* A0 = A + (size_t)(bm * 128 + w * 32 + crow) * 1024 + ce8;
  const us* A1 = A0 + (size_t)16 * 1024;
  const us* B0 = Bt + (size_t)(bn * 128 + w * 32 + crow) * 1024 + ce8;
  const us* B1 = B0 + (size_t)16 * 1024;
  const int dA0 = (w * 32) * 32, dA1 = (w * 32 + 16) * 32;

  // prologue: tile 0 -> buf 0
  gload16(A0, &lA[0][dA0]);
  gload16(A1, &lA[0][dA1]);
  gload16(B0, &lB[0][dA0]);
  gload16(B1, &lB[0][dA1]);

  int cur = 0, nxt = 1;
  for (int kt = 0; kt < 32; ++kt) {
    if (kt < 31) {
      int ko = (kt + 1) * 32;
      gload16(A0 + ko, &lA[nxt][dA0]);
      gload16(A1 + ko, &lA[nxt][dA1]);
      gload16(B0 + ko, &lB[nxt][dA0]);
      gload16(B1 + ko, &lB[nxt][dA1]);
      asm volatile("s_waitcnt vmcnt(4)" ::: "memory");
    } else {
      asm volatile("s_waitcnt vmcnt(0)" ::: "memory");
    }
    __builtin_amdgcn_s_barrier();
    __builtin_amdgcn_sched_barrier(0);

    short8 af[4], bfr[4];
#pragma unroll
    for (int i = 0; i < 4; ++i)
      af[i] = *reinterpret_cast<const short8*>(&lA[cur][(wr + i * 16 + lr) * 32 + lg * 8]);
#pragma unroll
    for (int j = 0; j < 4; ++j)
      bfr[j] = *reinterpret_cast<const short8*>(&lB[cur][(wc + j * 16 + lr) * 32 + lg * 8]);
    __builtin_amdgcn_s_setprio(1);
#pragma unroll
    for (int i = 0; i < 4; ++i)
#pragma unroll
      for (int j = 0; j < 4; ++j)
        acc[i][j] = __builtin_amdgcn_mfma_f32_16x16x32_bf16(af[i], bfr[j], acc[i][j], 0, 0, 0);
    __builtin_amdgcn_s_setprio(0);

    cur = nxt;
    nxt = (nxt == 2) ? 0 : nxt + 1;
  }
#pragma unroll
  for (int i = 0; i < 4; ++i)
#pragma unroll
    for (int j = 0; j < 4; ++j)
#pragma unroll
      for (int ii = 0; ii < 4; ++ii) {
        int r = bm * 128 + wr + i * 16 + lg * 4 + ii;
        int c = bn * 128 + wc + j * 16 + lr;
        float v = acc[i][j][ii] * oscale;
        int b = r >> 11, s = r & (S_ - 1), h = c >> 6, dk = c & 63;
        outH[(((size_t)(b * H_ + h) * S_ + s) * DK_) + dk] = f2bf(v);
      }
}

__global__ __launch_bounds__(256) void proj_gemm(const us* __restrict__ q_bf,
                                                 const us* __restrict__ k_bf,
                                                 const us* __restrict__ v_bf,
                                                 const us* __restrict__ Wq_bf,
                                                 const us* __restrict__ Wk_bf,
                                                 const us* __restrict__ Wv_bf,
                                                 us* __restrict__ Qh, us* __restrict__ Kh,
                                                 us* __restrict__ Vh) {
  if (blockIdx.y == 0) gemm_core_hs(q_bf, Wq_bf, Qh, QSCALE);
  else if (blockIdx.y == 1) gemm_core_hs(k_bf, Wk_bf, Kh, 1.0f);
  else gemm_core_hs(v_bf, Wv_bf, Vh, 1.0f);
}

// Wo GEMM: 128x64 tile, triple-buffered + counted vmcnt, fp32 output.
__global__ __launch_bounds__(256) void wo_gemm(const us* __restrict__ A,
                                               const us* __restrict__ Bt,
                                               float* __restrict__ outF) {
  __shared__ __align__(16) us lA[3][128 * 32];
  __shared__ __align__(16) us lB[3][64 * 32];
  const int tid = threadIdx.x;
  const int bm = blockIdx.x >> 4, bn = blockIdx.x & 15;
  const int w = tid >> 6, lane = tid & 63;
  const int lr = lane & 15, lg = lane >> 4;

  f32x4 acc[2][4];
#pragma unroll
  for (int i = 0; i < 2; ++i)
#pragma unroll
    for (int j = 0; j < 4; ++j) acc[i][j] = (f32x4){0.f, 0.f, 0.f, 0.f};

  const int crow = lane >> 2, ce8 = (lane & 3) * 8;
  const us* A0 = A + (size_t)(bm * 128 + w * 32 + crow) * 1024 + ce8;
  const us* A1 = A0 + (size_t)16 * 1024;
  const us* B0 = Bt + (size_t)(bn * 64 + w * 16 + crow) * 1024 + ce8;
  const int dA0 = (w * 32) * 32, dA1 = (w * 32 + 16) * 32, dB0 = (w * 16) * 32;

  gload16(A0, &lA[0][dA0]);
  gload16(A1, &lA[0][dA1]);
  gload16(B0, &lB[0][dB0]);

  int cur = 0, nxt = 1;
  for (int kt = 0; kt < 32; ++kt) {
    if (kt < 31) {
      int ko = (kt + 1) * 32;
      gload16(A0 + ko, &lA[nxt][dA0]);
      gload16(A1 + ko, &lA[nxt][dA1]);
      gload16(B0 + ko, &lB[nxt][dB0]);
      asm volatile("s_waitcnt vmcnt(3)" ::: "memory");
    } else {
      asm volatile("s_waitcnt vmcnt(0)" ::: "memory");
    }
    __builtin_amdgcn_s_barrier();
    __builtin_amdgcn_sched_barrier(0);

    short8 af[2], bfr[4];
#pragma unroll
    for (int i = 0; i < 2; ++i)
      af[i] = *reinterpret_cast<const short8*>(&lA[cur][(w * 32 + i * 16 + lr) * 32 + lg * 8]);
#pragma unroll
    for (int j = 0; j < 4; ++j)
      bfr[j] = *reinterpret_cast<const short8*>(&lB[cur][(j * 16 + lr) * 32 + lg * 8]);
    __builtin_amdgcn_s_setprio(1);
#pragma unroll
    for (int i = 0; i < 2; ++i)
#pragma unroll
      for (int j = 0; j < 4; ++j)
        acc[i][j] = __builtin_amdgcn_mfma_f32_16x16x32_bf16(af[i], bfr[j], acc[i][j], 0, 0, 0);
    __builtin_amdgcn_s_setprio(0);

    cur = nxt;
    nxt = (nxt == 2) ? 0 : nxt + 1;
  }
#pragma unroll
  for (int i = 0; i < 2; ++i)
#pragma unroll
    for (int j = 0; j < 4; ++j)
#pragma unroll
      for (int ii = 0; ii < 4; ++ii) {
        int r = bm * 128 + w * 32 + i * 16 + lg * 4 + ii;
        int c = bn * 64 + j * 16 + lr;
        outF[(size_t)r * 1024 + c] = acc[i][j][ii];
      }
}

// Vh [B,H,S,DK] -> VhTw [B,H,DK,S] with reach weighting folded in.
__global__ __launch_bounds__(256) void transp_kernel(const us* __restrict__ Vh,
                                                     const float* __restrict__ reaches,
                                                     us* __restrict__ VhTw) {
  __shared__ us t[64 * 68];
  const int bh = blockIdx.x >> 5, st = blockIdx.x & 31;
  const int b = bh >> 4;
  const size_t base = (size_t)bh * S_ * DK_;
  const int r = threadIdx.x >> 3, e8 = (threadIdx.x & 7) * 8;
#pragma unroll
  for (int h2 = 0; h2 < 2; ++h2) {
    int row = r + h2 * 32;
    *reinterpret_cast<short8*>(&t[row * 68 + e8]) =
        *reinterpret_cast<const short8*>(&Vh[base + (size_t)(st * 64 + row) * DK_ + e8]);
  }
  __syncthreads();
#pragma unroll
  for (int h2 = 0; h2 < 2; ++h2) {
    int dk = (threadIdx.x >> 3) + h2 * 32;
    int sc = (threadIdx.x & 7) * 8;
    short8 v;
#pragma unroll
    for (int j = 0; j < 8; ++j) {
      float rw = reaches[b * S_ + st * 64 + sc + j];
      v[j] = (short)f2bf_hw(bf2f(t[(sc + j) * 68 + dk]) * rw);
    }
    *reinterpret_cast<short8*>(&VhTw[base + (size_t)dk * S_ + st * 64 + sc]) = v;
  }
}

// 32x32-MFMA streaming-softmax attention, swapped QK^T + in-register P.
// K/V' in triple-buffered swizzled LDS via global_load_lds (pre-swizzled source),
// counted vmcnt, ONE raw barrier per kt.
__global__ __launch_bounds__(256, 2) void attn_kernel(const us* __restrict__ Qh,
                                                      const us* __restrict__ Kh,
                                                      const us* __restrict__ Vh,
                                                      const us* __restrict__ VhTw,
                                                      const float* __restrict__ reaches,
                                                      const float* __restrict__ rsum,
                                                      us* __restrict__ concat) {
  // buf layout: [3][ K 64x64 | V 64x64 ] elements
  __shared__ __align__(16) us sbuf[3][8192];
  __shared__ float diagP[128];
  __shared__ float lsum[128];

  const int tid = threadIdx.x;
  const int bid = ((blockIdx.x & 7) << 6) | (blockIdx.x >> 3);  // XCD swizzle (512 = 8*64)
  const int qt = bid & 15;
  const int bh = bid >> 4;
  const int b = bh >> 4, h = bh & 15;
  const size_t base = (size_t)bh * S_ * DK_;

  const int w = tid >> 6, lane = tid & 63;
  const int l31 = lane & 31, hh = lane >> 5, l7 = lane & 7;
  const int h4 = hh * 4;
  const int diagkt = qt * 2 + (w >> 1);

  // staging source (pre-swizzled global address; LDS dest linear):
  // wave w stages K rows [16w,16w+16) and V d-rows [16w,16w+16), 2 issues each.
  const int Lrow = lane >> 3;            // 0..7 within an 8-row issue
  const int cswz = (l7 ^ Lrow) << 3;     // swizzled column slot * 8
  const us* Kg0 = Kh + base + (size_t)(w * 16 + Lrow) * DK_ + cswz;
  const us* Kg1 = Kg0 + (size_t)8 * DK_;
  const us* Vg0 = VhTw + base + (size_t)(w * 16 + Lrow) * S_ + cswz;
  const us* Vg1 = Vg0 + (size_t)8 * S_;
  const int dK0 = (w * 16) * 64, dK1 = (w * 16 + 8) * 64;
  const int dV0 = 4096 + dK0, dV1 = 4096 + dK1;

  // Q fragments (B-operand for swapped QK)
  short8 aq[4];
  {
    const us* qp = &Qh[base + (size_t)(qt * 128 + w * 32 + l31) * DK_ + hh * 8];
#pragma unroll
    for (int dk = 0; dk < 4; ++dk)
      aq[dk] = *reinterpret_cast<const short8*>(qp + dk * 16);
  }

  // loop-invariant swizzled LDS read offsets
  int rdK[2][4];
#pragma unroll
  for (int c = 0; c < 2; ++c)
#pragma unroll
    for (int dk = 0; dk < 4; ++dk)
      rdK[c][dk] = (c * 32 + l31) * 64 + (((dk * 2 + hh) ^ l7) << 3);

  // prologue: tile 0 -> buf 0
  gload16(Kg0, &sbuf[0][dK0]);
  gload16(Kg1, &sbuf[0][dK1]);
  gload16(Vg0, &sbuf[0][dV0]);
  gload16(Vg1, &sbuf[0][dV1]);

  f32x16 oacc[2];
  float lacc = 0.f;
#pragma unroll
  for (int c = 0; c < 2; ++c)
#pragma unroll
    for (int r = 0; r < 16; ++r) oacc[c][r] = 0.f;

  int cur = 0, nxt = 1;
  for (int kt = 0; kt < 32; ++kt) {
    if (kt < 31) {
      const size_t ko = (size_t)(kt + 1) * 64;
      gload16(Kg0 + ko * DK_, &sbuf[nxt][dK0]);
      gload16(Kg1 + ko * DK_, &sbuf[nxt][dK1]);
      gload16(Vg0 + ko, &sbuf[nxt][dV0]);
      gload16(Vg1 + ko, &sbuf[nxt][dV1]);
      asm volatile("s_waitcnt vmcnt(4)" ::: "memory");
    } else {
      asm volatile("s_waitcnt vmcnt(0)" ::: "memory");
    }
    __builtin_amdgcn_s_barrier();
    __builtin_amdgcn_sched_barrier(0);

    const us* lKc = &sbuf[cur][0];
    const us* vTc = &sbuf[cur][4096];

    // swapped QK^T: st_c[k][q] = mfma(A=K chunk c, B=Q)
    f32x16 st0, st1;
#pragma unroll
    for (int r = 0; r < 16; ++r) { st0[r] = 0.f; st1[r] = 0.f; }
    __builtin_amdgcn_s_setprio(1);
#pragma unroll
    for (int dk = 0; dk < 4; ++dk) {
      short8 k0 = *reinterpret_cast<const short8*>(&lKc[rdK[0][dk]]);
      st0 = __builtin_amdgcn_mfma_f32_32x32x16_bf16(k0, aq[dk], st0, 0, 0, 0);
      short8 k1 = *reinterpret_cast<const short8*>(&lKc[rdK[1][dk]]);
      st1 = __builtin_amdgcn_mfma_f32_32x32x16_bf16(k1, aq[dk], st1, 0, 0, 0);
    }
    __builtin_amdgcn_s_setprio(0);

    // streaming softmax fully in-register
    float e0[16], e1[16];
#pragma unroll
    for (int r = 0; r < 16; ++r) {
      e0[r] = __builtin_amdgcn_exp2f(st0[r]);
      e1[r] = __builtin_amdgcn_exp2f(st1[r]);
      lacc += e0[r] + e1[r];
    }
    if (kt == diagkt) {
#pragma unroll
      for (int r = 0; r < 16; ++r) {
        int kk = (r & 3) + 8 * (r >> 2) + 4 * hh;
        float ev = (w & 1) ? e1[r] : e0[r];
        if (kk == l31) diagP[w * 32 + l31] = ev;
      }
    }

    // P -> bf16 A-frags via cvt_pk + permlane32_swap
    short8 pa[4];
#pragma unroll
    for (int ks = 0; ks < 4; ++ks) {
      const int ro = (ks & 1) * 8;
      unsigned d0, s0, d1, s1;
      if (ks < 2) {
        d0 = cvtpk(e0[ro + 0], e0[ro + 1]);
        s0 = cvtpk(e0[ro + 4], e0[ro + 5]);
        d1 = cvtpk(e0[ro + 2], e0[ro + 3]);
        s1 = cvtpk(e0[ro + 6], e0[ro + 7]);
      } else {
        d0 = cvtpk(e1[ro + 0], e1[ro + 1]);
        s0 = cvtpk(e1[ro + 4], e1[ro + 5]);
        d1 = cvtpk(e1[ro + 2], e1[ro + 3]);
        s1 = cvtpk(e1[ro + 6], e1[ro + 7]);
      }
      asm("v_permlane32_swap_b32 %0, %1" : "+v"(d0), "+v"(s0));
      asm("v_permlane32_swap_b32 %0, %1" : "+v"(d1), "+v"(s1));
      union { unsigned u[4]; short8 v; } pk;
      pk.u[0] = d0; pk.u[1] = d1; pk.u[2] = s0; pk.u[3] = s1;
      pa[ks] = pk.v;
    }

    // PV: O[q][d] += P * V'
    __builtin_amdgcn_s_setprio(1);
#pragma unroll
    for (int dc = 0; dc < 2; ++dc)
#pragma unroll
      for (int ks = 0; ks < 4; ++ks) {
        short8 bv = *reinterpret_cast<const short8*>(&vTc[rdK[dc][ks]]);
        oacc[dc] = __builtin_amdgcn_mfma_f32_32x32x16_bf16(pa[ks], bv, oacc[dc], 0, 0, 0);
      }
    __builtin_amdgcn_s_setprio(0);

    cur = nxt;
    nxt = (nxt == 2) ? 0 : nxt + 1;
  }

  // total l per q: merge the two hh halves, broadcast via LDS
  lacc += __shfl_xor(lacc, 32, 64);
  if (hh == 0) lsum[w * 32 + l31] = lacc;
  __syncthreads();

  const float rb = rsum[b];
#pragma unroll
  for (int r = 0; r < 16; ++r) {
    const int q = w * 32 + (r & 3) + 8 * (r >> 2) + h4;
    const int qg = qt * 128 + q;
    const float rq = reaches[b * S_ + qg];
    const float contrib = (rb - rq) / (rb + 1e-9f) * (1.f - rq) * 100.f;
    const float corr = 0.999999f * diagP[q] * rq;
    const float linv = 1.0f / lsum[q];
#pragma unroll
    for (int dc = 0; dc < 2; ++dc) {
      int d = dc * 32 + l31;
      float vhv = bf2f(Vh[base + (size_t)qg * DK_ + d]);
      float pv = (oacc[dc][r] - corr * vhv) * linv;
      float o = (vhv - pv) * contrib;
      concat[((size_t)(b * S_ + qg)) * D_ + h * 64 + d] = f2bf(o);
    }
  }
}

extern "C" void kernel_launch(void* const* d_in, const int* in_sizes, int n_in,
                              void* d_out, int out_size, void* d_ws, size_t ws_size,
                              hipStream_t stream) {
  const float* q = (const float*)d_in[0];
  const float* k = (const float*)d_in[1];
  const float* v = (const float*)d_in[2];
  const float* reaches = (const float*)d_in[3];
  const float* Wq = (const float*)d_in[4];
  const float* Wk = (const float*)d_in[5];
  const float* Wv = (const float*)d_in[6];
  const float* Wo = (const float*)d_in[7];

  const size_t NQKV = (size_t)B_ * S_ * D_;
  const size_t NW = (size_t)D_ * D_;

  us* q_bf = (us*)d_ws;
  us* k_bf = q_bf + NQKV;
  us* v_bf = k_bf + NQKV;
  us* Wq_bf = v_bf + NQKV;
  us* Wk_bf = Wq_bf + NW;
  us* Wv_bf = Wk_bf + NW;
  us* Wo_bf = Wv_bf + NW;
  us* Qh = Wo_bf + NW;
  us* Kh = Qh + NQKV;
  us* Vh = Kh + NQKV;
  us* concat = Vh + NQKV;
  float* rs = (float*)(concat + NQKV);
  us* VhTw = q_bf;  // alias: q_bf dead after proj_gemm

  cvt_all<<<16384, 256, 0, stream>>>(q, k, v, Wq, Wk, Wv, Wo,
                                     q_bf, k_bf, v_bf, Wq_bf, Wk_bf, Wv_bf, Wo_bf);
  rs_kernel<<<B_, 256, 0, stream>>>(reaches, rs);

  proj_gemm<<<dim3(256, 3), 256, 0, stream>>>(q_bf, k_bf, v_bf, Wq_bf, Wk_bf, Wv_bf, Qh, Kh, Vh);
  transp_kernel<<<B_ * H_ * (S_ / 64), 256, 0, stream>>>(Vh, reaches, VhTw);

  attn_kernel<<<B_ * H_ * (S_ / 128), 256, 0, stream>>>(Qh, Kh, Vh, VhTw, reaches, rs, concat);

  wo_gemm<<<512, 256, 0, stream>>>(concat, Wo_bf, (float*)d_out);
}